// Round 3
// baseline (584.484 us; speedup 1.0000x reference)
//
#include <hip/hip_runtime.h>
#include <stdint.h>

#define NT 4096     // tokens
#define HD 1024     // hidden
#define ID 512      // intermediate
#define RE 32       // routed experts
#define EE 40       // total experts
#define KT 4        // top-k
#define CAPACITY 768

typedef __bf16 bf16x8 __attribute__((ext_vector_type(8)));
typedef float f32x4 __attribute__((ext_vector_type(4)));
typedef unsigned int u32x4 __attribute__((ext_vector_type(4)));
typedef unsigned short u16x4 __attribute__((ext_vector_type(4)));

__device__ __forceinline__ float bf2f(unsigned short u) {
    union { unsigned int i; float f; } v; v.i = ((unsigned int)u) << 16; return v.f;
}
__device__ __forceinline__ unsigned short f2bf(float f) {
    union { float f; unsigned int i; } v; v.f = f;
    unsigned int u = v.i;
    return (unsigned short)((u + 0x7fffu + ((u >> 16) & 1u)) >> 16);
}

// Load 8 contiguous logical elements [ei..ei+8) as packed bf16 (u32x4).
// inF32=0: buffer is bf16 bits -> direct 16B load.
// inF32=1: buffer is f32 -> two 16B loads + RNE convert/pack.
__device__ __forceinline__ u32x4 ld8(const void* p, size_t ei, int inF32) {
    if (!inF32) {
        return *(const u32x4*)((const unsigned short*)p + ei);
    } else {
        const float* f = (const float*)p + ei;
        f32x4 a = *(const f32x4*)f;
        f32x4 b = *(const f32x4*)(f + 4);
        u32x4 r;
        r[0] = (unsigned)f2bf(a[0]) | ((unsigned)f2bf(a[1]) << 16);
        r[1] = (unsigned)f2bf(a[2]) | ((unsigned)f2bf(a[3]) << 16);
        r[2] = (unsigned)f2bf(b[0]) | ((unsigned)f2bf(b[1]) << 16);
        r[3] = (unsigned)f2bf(b[2]) | ((unsigned)f2bf(b[3]) << 16);
        return r;
    }
}

// ---------------- dtype detection ----------------
// flags[0] = 1 iff float tensors are fp32 (else bf16 bits)
// flags[1] = 1 iff top_k_index is int64 (else int32)
__global__ __launch_bounds__(256) void detect_k(const void* __restrict__ X,
                                                const void* __restrict__ idx,
                                                int* __restrict__ flags) {
    __shared__ int sInsane, sOddNZ;
    const int tid = threadIdx.x;
    if (tid == 0) { sInsane = 0; sOddNZ = 0; }
    __syncthreads();
    // bf16-vs-f32: bf16 N(0,1)-scale data never has |x| >= 2^17; f32 low-halves do ~44% of the time.
    const unsigned short* xu = (const unsigned short*)X;
    int cnt = 0;
    for (int i = tid; i < 8192; i += 256) {
        int e = (xu[i] >> 7) & 0xFF;
        if (e >= 0x90) cnt++;
    }
    if (cnt) atomicAdd(&sInsane, cnt);
    // int32-vs-int64: int64 little-endian => every odd int32 word is 0 (values in [0,40)).
    const int* ip = (const int*)idx;
    int odd = 0;
    for (int i = tid; i < 512; i += 256)
        if ((i & 1) && ip[i] != 0) odd++;
    if (odd) atomicAdd(&sOddNZ, odd);
    __syncthreads();
    if (tid == 0) {
        flags[0] = (sInsane > 64) ? 1 : 0;
        flags[1] = (sOddNZ == 0) ? 1 : 0;
    }
}

// ---------------- routing: slot assignment per (token,k) assignment ----------------
__global__ __launch_bounds__(256) void route_k(const int* __restrict__ idx,
                                               const int* __restrict__ flags,
                                               int* __restrict__ cnt,
                                               int* __restrict__ tok,
                                               int* __restrict__ smap) {
    int a = blockIdx.x * 256 + threadIdx.x;
    if (a >= NT * KT) return;
    const int isI64 = flags[1];
    int e = isI64 ? idx[a << 1] : idx[a];
    int s = -1;
    if (e < RE) {
        int slot = atomicAdd(&cnt[e], 1);
        if (slot < CAPACITY) {
            tok[e * CAPACITY + slot] = a >> 2;   // token id
            s = slot;
        }
    }
    smap[a] = s;
}

// ---------------- GEMM1: gathered X @ W1^T (gate & up halves) + silu -> mid ----------------
// grid: (6 mtiles, 4 ntiles over I, 32 experts); block 256 = 4 waves (2x2 of 64x64)
__global__ __launch_bounds__(256, 2) void gemm1_k(
    const void* __restrict__ X,              // [NT][HD] bf16 or f32
    const void* __restrict__ W1,             // [EE][2*ID][HD] bf16 or f32
    const int* __restrict__ flags,
    const int* __restrict__ cnts,
    const int* __restrict__ tok,
    unsigned short* __restrict__ mid)        // [RE][CAPACITY][ID] bf16 bits
{
    const int e = blockIdx.z;
    int cnt = cnts[e]; if (cnt > CAPACITY) cnt = CAPACITY;
    const int m0 = blockIdx.x * 128;
    if (m0 >= cnt) return;
    const int n0 = blockIdx.y * 128;
    const int inF32 = flags[0];

    __shared__ unsigned short Ash[4 * 128 * 8];  // 8 KB, chunk16 = kc*128 + row
    __shared__ unsigned short Bgs[4 * 128 * 8];
    __shared__ unsigned short Bus[4 * 128 * 8];

    const int tid  = threadIdx.x;
    const int lane = tid & 63;
    const int wv   = tid >> 6;
    const int wm   = wv >> 1, wn = wv & 1;
    const int q    = lane >> 4, ln = lane & 15;

    const int row = tid & 127;     // staging row (both A-row and B-row)
    const int kcb = tid >> 7;      // 0/1; chunk kc = kcb + 2*i

    const int trow = (m0 + row < cnt) ? tok[e * CAPACITY + m0 + row] : 0;
    const size_t aOff = (size_t)trow * HD;
    const size_t gOff = ((size_t)e * 2 * ID + (n0 + row)) * HD;
    const size_t uOff = ((size_t)e * 2 * ID + (ID + n0 + row)) * HD;

    f32x4 accg[4][4], accu[4][4];
    const f32x4 z4 = {0.f, 0.f, 0.f, 0.f};
    #pragma unroll
    for (int a_ = 0; a_ < 4; a_++)
        #pragma unroll
        for (int b_ = 0; b_ < 4; b_++) { accg[a_][b_] = z4; accu[a_][b_] = z4; }

    u32x4 va[2], vg[2], vu[2];
    #pragma unroll
    for (int i = 0; i < 2; i++) {
        int kc = kcb + 2 * i;
        va[i] = ld8(X,  aOff + kc * 8, inF32);
        vg[i] = ld8(W1, gOff + kc * 8, inF32);
        vu[i] = ld8(W1, uOff + kc * 8, inF32);
    }

    for (int k0 = 0; k0 < HD; k0 += 32) {
        __syncthreads();
        #pragma unroll
        for (int i = 0; i < 2; i++) {
            int kc = kcb + 2 * i;
            *(u32x4*)&Ash[(kc * 128 + row) * 8] = va[i];
            *(u32x4*)&Bgs[(kc * 128 + row) * 8] = vg[i];
            *(u32x4*)&Bus[(kc * 128 + row) * 8] = vu[i];
        }
        __syncthreads();
        if (k0 + 32 < HD) {
            #pragma unroll
            for (int i = 0; i < 2; i++) {
                int kc = kcb + 2 * i;
                va[i] = ld8(X,  aOff + k0 + 32 + kc * 8, inF32);
                vg[i] = ld8(W1, gOff + k0 + 32 + kc * 8, inF32);
                vu[i] = ld8(W1, uOff + k0 + 32 + kc * 8, inF32);
            }
        }
        bf16x8 af[4], bgf[4], buf2[4];
        #pragma unroll
        for (int mt = 0; mt < 4; mt++)
            af[mt] = *(const bf16x8*)&Ash[(q * 128 + wm * 64 + mt * 16 + ln) * 8];
        #pragma unroll
        for (int nt = 0; nt < 4; nt++) {
            bgf[nt]  = *(const bf16x8*)&Bgs[(q * 128 + wn * 64 + nt * 16 + ln) * 8];
            buf2[nt] = *(const bf16x8*)&Bus[(q * 128 + wn * 64 + nt * 16 + ln) * 8];
        }
        #pragma unroll
        for (int mt = 0; mt < 4; mt++)
            #pragma unroll
            for (int nt = 0; nt < 4; nt++) {
                accg[mt][nt] = __builtin_amdgcn_mfma_f32_16x16x32_bf16(af[mt], bgf[nt],  accg[mt][nt], 0, 0, 0);
                accu[mt][nt] = __builtin_amdgcn_mfma_f32_16x16x32_bf16(af[mt], buf2[nt], accu[mt][nt], 0, 0, 0);
            }
    }

    // epilogue: mid = silu(gate)*up, bf16; C/D layout: col=lane&15, row=q*4+r
    const size_t midBase = (size_t)e * CAPACITY;
    #pragma unroll
    for (int mt = 0; mt < 4; mt++) {
        #pragma unroll
        for (int r = 0; r < 4; r++) {
            int slot = m0 + wm * 64 + mt * 16 + q * 4 + r;
            if (slot < cnt) {
                unsigned short* dst = mid + (midBase + slot) * ID;
                #pragma unroll
                for (int nt = 0; nt < 4; nt++) {
                    int i_col = n0 + wn * 64 + nt * 16 + ln;
                    float gv = accg[mt][nt][r];
                    float uv = accu[mt][nt][r];
                    float sv = gv / (1.f + __expf(-gv));
                    dst[i_col] = f2bf(sv * uv);
                }
            }
        }
    }
}

// ---------------- GEMM2: mid @ W2^T -> ybuf ----------------
// grid: (6 mtiles, 8 ntiles over H, 32 experts)
__global__ __launch_bounds__(256, 2) void gemm2_k(
    const unsigned short* __restrict__ mid,  // [RE][CAPACITY][ID] bf16 (internal)
    const void* __restrict__ W2,             // [RE][HD][ID] bf16 or f32
    const int* __restrict__ flags,
    const int* __restrict__ cnts,
    unsigned short* __restrict__ ybuf)       // [RE][CAPACITY][HD] bf16 bits
{
    const int e = blockIdx.z;
    int cnt = cnts[e]; if (cnt > CAPACITY) cnt = CAPACITY;
    const int m0 = blockIdx.x * 128;
    if (m0 >= cnt) return;
    const int n0 = blockIdx.y * 128;
    const int inF32 = flags[0];

    __shared__ unsigned short Ash[4 * 128 * 8];
    __shared__ unsigned short Bsh[4 * 128 * 8];

    const int tid  = threadIdx.x;
    const int lane = tid & 63;
    const int wv   = tid >> 6;
    const int wm   = wv >> 1, wn = wv & 1;
    const int q    = lane >> 4, ln = lane & 15;

    const int row = tid & 127;
    const int kcb = tid >> 7;

    const unsigned short* aBase = mid + ((size_t)e * CAPACITY + m0 + row) * ID;
    const size_t bOff = ((size_t)e * HD + n0 + row) * ID;

    f32x4 acc[4][4];
    const f32x4 z4 = {0.f, 0.f, 0.f, 0.f};
    #pragma unroll
    for (int a_ = 0; a_ < 4; a_++)
        #pragma unroll
        for (int b_ = 0; b_ < 4; b_++) acc[a_][b_] = z4;

    u32x4 va[2], vb[2];
    #pragma unroll
    for (int i = 0; i < 2; i++) {
        int kc = kcb + 2 * i;
        va[i] = *(const u32x4*)(aBase + kc * 8);
        vb[i] = ld8(W2, bOff + kc * 8, inF32);
    }

    for (int k0 = 0; k0 < ID; k0 += 32) {
        __syncthreads();
        #pragma unroll
        for (int i = 0; i < 2; i++) {
            int kc = kcb + 2 * i;
            *(u32x4*)&Ash[(kc * 128 + row) * 8] = va[i];
            *(u32x4*)&Bsh[(kc * 128 + row) * 8] = vb[i];
        }
        __syncthreads();
        if (k0 + 32 < ID) {
            #pragma unroll
            for (int i = 0; i < 2; i++) {
                int kc = kcb + 2 * i;
                va[i] = *(const u32x4*)(aBase + k0 + 32 + kc * 8);
                vb[i] = ld8(W2, bOff + k0 + 32 + kc * 8, inF32);
            }
        }
        bf16x8 af[4], bf[4];
        #pragma unroll
        for (int mt = 0; mt < 4; mt++)
            af[mt] = *(const bf16x8*)&Ash[(q * 128 + wm * 64 + mt * 16 + ln) * 8];
        #pragma unroll
        for (int nt = 0; nt < 4; nt++)
            bf[nt] = *(const bf16x8*)&Bsh[(q * 128 + wn * 64 + nt * 16 + ln) * 8];
        #pragma unroll
        for (int mt = 0; mt < 4; mt++)
            #pragma unroll
            for (int nt = 0; nt < 4; nt++)
                acc[mt][nt] = __builtin_amdgcn_mfma_f32_16x16x32_bf16(af[mt], bf[nt], acc[mt][nt], 0, 0, 0);
    }

    const size_t yBase = (size_t)e * CAPACITY;
    #pragma unroll
    for (int mt = 0; mt < 4; mt++) {
        #pragma unroll
        for (int r = 0; r < 4; r++) {
            int slot = m0 + wm * 64 + mt * 16 + q * 4 + r;
            if (slot < cnt) {
                unsigned short* dst = ybuf + (yBase + slot) * HD;
                #pragma unroll
                for (int nt = 0; nt < 4; nt++) {
                    int h = n0 + wn * 64 + nt * 16 + ln;
                    dst[h] = f2bf(acc[mt][nt][r]);
                }
            }
        }
    }
}

// ---------------- gather: out[t] = zero_w*x[t] + sum_k w_k * ybuf[e_k, slot_k] (fp32 out) ----------------
__global__ __launch_bounds__(256) void gather_k(
    const void* __restrict__ X,
    const int* __restrict__ idx,
    const void* __restrict__ wts,
    const int* __restrict__ flags,
    const int* __restrict__ smap,
    const unsigned short* __restrict__ ybuf,
    float* __restrict__ out)
{
    const int t = blockIdx.x;
    const int tid = threadIdx.x;
    const int inF32 = flags[0];
    __shared__ int se[KT];
    __shared__ float sw[KT];
    __shared__ int ss[KT];
    if (tid < KT) {
        const int isI64 = flags[1];
        int a = t * KT + tid;
        se[tid] = isI64 ? idx[a << 1] : idx[a];
        sw[tid] = inF32 ? ((const float*)wts)[a] : bf2f(((const unsigned short*)wts)[a]);
        ss[tid] = smap[a];
    }
    __syncthreads();

    const int h = tid * 4;
    float x0, x1, x2, x3;
    if (inF32) {
        f32x4 xv = *(const f32x4*)((const float*)X + (size_t)t * HD + h);
        x0 = xv[0]; x1 = xv[1]; x2 = xv[2]; x3 = xv[3];
    } else {
        u16x4 xv = *(const u16x4*)((const unsigned short*)X + (size_t)t * HD + h);
        x0 = bf2f(xv[0]); x1 = bf2f(xv[1]); x2 = bf2f(xv[2]); x3 = bf2f(xv[3]);
    }
    float zw = 0.f;
    #pragma unroll
    for (int k = 0; k < KT; k++)
        if (se[k] >= RE) zw += sw[k];

    float a0 = zw * x0, a1 = zw * x1, a2 = zw * x2, a3 = zw * x3;

    #pragma unroll
    for (int k = 0; k < KT; k++) {
        if (se[k] < RE && ss[k] >= 0) {
            u16x4 yv = *(const u16x4*)&ybuf[((size_t)se[k] * CAPACITY + ss[k]) * HD + h];
            float w = sw[k];
            a0 += w * bf2f(yv[0]);
            a1 += w * bf2f(yv[1]);
            a2 += w * bf2f(yv[2]);
            a3 += w * bf2f(yv[3]);
        }
    }
    f32x4 o = {a0, a1, a2, a3};
    *(f32x4*)&out[(size_t)t * HD + h] = o;
}

extern "C" void kernel_launch(void* const* d_in, const int* in_sizes, int n_in,
                              void* d_out, int out_size, void* d_ws, size_t ws_size,
                              hipStream_t stream) {
    (void)in_sizes; (void)n_in; (void)out_size; (void)ws_size;
    const void* X   = d_in[0];             // hidden_states (bf16 or f32 — detected)
    const int*  idx = (const int*)d_in[1]; // top_k_index (int32 or int64 — detected)
    const void* wts = d_in[2];             // top_k_weights
    const void* W1  = d_in[3];             // gate_up_proj
    const void* W2  = d_in[4];             // down_proj
    float* out = (float*)d_out;            // fp32 output (reference output dtype)

    char* ws = (char*)d_ws;
    int* flags = (int*)ws;                             // 8 B (128 B reserved)
    int* cnt   = (int*)(ws + 128);                     // 128 B
    int* tok   = (int*)(ws + 256);                     // 32*768*4   = 98304 B
    int* smap  = (int*)(ws + 256 + 98304);             // 16384*4    = 65536 B
    unsigned short* mid  = (unsigned short*)(ws + 164224);             // 25165824 B
    unsigned short* ybuf = (unsigned short*)(ws + 164224 + 25165824);  // 50331648 B

    hipMemsetAsync(ws, 0, 256, stream);  // flags + cnt
    detect_k<<<dim3(1), dim3(256), 0, stream>>>(X, idx, flags);
    route_k<<<dim3(64), dim3(256), 0, stream>>>(idx, flags, cnt, tok, smap);
    gemm1_k<<<dim3(6, 4, 32), dim3(256), 0, stream>>>(X, W1, flags, cnt, tok, mid);
    gemm2_k<<<dim3(6, 8, 32), dim3(256), 0, stream>>>(mid, W2, flags, cnt, ybuf);
    gather_k<<<dim3(4096), dim3(256), 0, stream>>>(X, idx, wts, flags, smap, ybuf, out);
}